// Round 6
// baseline (680.931 us; speedup 1.0000x reference)
//
#include <hip/hip_runtime.h>

// ============================================================================
// GLM4-MoE attention layer on MI355X (gfx950), fp16 MFMA pipeline.
// Round 6: GEMM inner-loop rewrite (geometry/swizzle/staging unchanged):
//   - fragment register double-buffer: ds_reads for phase p+1 issued before
//     phase p's MFMA cluster -> LDS pipe overlaps MFMA pipe within each wave
//   - 2 barriers per K-tile (was 8): pre-stage (WAR) + post-vmcnt (RAW)
//   - counted s_waitcnt vmcnt(8): tile t+1 guaranteed landed, tile t+2's 8
//     loads stay in flight across the barrier (issue->drain ~4 phases)
// Attention v4 (round-5) and aux kernels unchanged.
// ============================================================================

typedef _Float16 f16;
typedef _Float16 f16x8 __attribute__((ext_vector_type(8)));
typedef float f32x4 __attribute__((ext_vector_type(4)));

static constexpr int Bn = 2, Sn = 2048, Hn = 4096, NH = 32, NKV = 8, HD = 128;
static constexpr float QSC = 0.08838834764831845f * 1.44269504088896340736f; // 1/sqrt(128)*log2e

#define AS1 __attribute__((address_space(1)))
#define AS3 __attribute__((address_space(3)))

__device__ __forceinline__ void async_ld16(const void* g, void* l) {
    __builtin_amdgcn_global_load_lds((const AS1 void*)g, (AS3 void*)l, 16, 0, 0);
}

__device__ __forceinline__ unsigned pk2(float a, float b) {
    unsigned r;
    asm("v_cvt_pkrtz_f16_f32 %0, %1, %2" : "=v"(r) : "v"(a), "v"(b));
    return r;
}

// native exp2: v_exp_f32 computes 2^x
__device__ __forceinline__ float fexp2(float x) {
    float r;
    asm("v_exp_f32 %0, %1" : "=v"(r) : "v"(x));
    return r;
}

// ---------------------------------------------------------------------------
__global__ void k_cvt(const float* __restrict__ src, f16* __restrict__ dst, long n) {
    long i = ((long)blockIdx.x * blockDim.x + threadIdx.x) * 8;
    if (i >= n) return;
    float4 a = *(const float4*)(src + i);
    float4 b = *(const float4*)(src + i + 4);
    f16x8 o = {(f16)a.x, (f16)a.y, (f16)a.z, (f16)a.w,
               (f16)b.x, (f16)b.y, (f16)b.z, (f16)b.w};
    *(f16x8*)(dst + i) = o;
}

// ---------------------------------------------------------------------------
__global__ void k_tcvt(const float* __restrict__ src, f16* __restrict__ dst,
                       int K, int N, long rs) {
    __shared__ float tile[32][33];
    int k0 = blockIdx.y * 32, n0 = blockIdx.x * 32;
    int tx = threadIdx.x, ty = threadIdx.y;
#pragma unroll
    for (int r = ty; r < 32; r += 8)
        tile[r][tx] = src[(long)(k0 + r) * N + (n0 + tx)];
    __syncthreads();
#pragma unroll
    for (int r = ty; r < 32; r += 8)
        dst[(long)(n0 + r) * rs + (k0 + tx)] = (f16)tile[tx][r];
}

// ---------------------------------------------------------------------------
__global__ void k_rope(f16* __restrict__ x, const float* __restrict__ cosb,
                       const float* __restrict__ sinb, int nheads) {
    long idx = (long)blockIdx.x * blockDim.x + threadIdx.x;
    int i = (int)(idx & 31);
    long t = idx >> 5;
    int s = (int)(t & (Sn - 1));
    int bh = (int)(t >> 11);
    int b = bh / nheads;
    long base = t * HD + 2 * i;
    float c = cosb[((long)b * Sn + s) * 64 + i];
    float sv = sinb[((long)b * Sn + s) * 64 + i];
    float x0 = (float)x[base], x1 = (float)x[base + 1];
    x[base]     = (f16)(x0 * c - x1 * sv);
    x[base + 1] = (f16)(x1 * c + x0 * sv);
}

// ---------------------------------------------------------------------------
__global__ void k_tv(const f16* __restrict__ v, f16* __restrict__ vt) {
    __shared__ f16 tile[32][33];
    int bk = blockIdx.z;
    int s0 = blockIdx.x * 32, d0 = blockIdx.y * 32;
    const f16* src = v + (long)bk * Sn * HD;
    f16* dst = vt + (long)bk * Sn * HD;
    int tx = threadIdx.x, ty = threadIdx.y;
#pragma unroll
    for (int r = ty; r < 32; r += 8)
        tile[r][tx] = src[(long)(s0 + r) * HD + (d0 + tx)];
    __syncthreads();
#pragma unroll
    for (int r = ty; r < 32; r += 8)
        dst[(long)(d0 + r) * Sn + (s0 + tx)] = tile[tx][r];
}

// ---------------------------------------------------------------------------
// 256x256 GEMM core v2, BK=64, 8 waves (2M x 4N), K=4096.
// LDS 128KB: buf c at c*65536; A at +0 (256x64), B at +32768 (256x64),
// rows 128B, swizzled byte cb ^ ((row&7)<<4). Staging identical to r4/r5.
// Schedule per K-tile: 4 MFMA phases with register-double-buffered fragments
// (reads issued one phase early), then {barrier; STAGE(t+2); vmcnt(8);
// barrier; preload next tile's first fragments}.
__device__ __forceinline__ void gemm256_core(
    const f16* __restrict__ A, const f16* __restrict__ Bt,
    char* L, int m0, int n0, f32x4 acc[8][4]) {
    const int t = threadIdx.x, lane = t & 63, wave = t >> 6;
    const int wm = wave >> 2, wn = wave & 3;
    const int fr = lane & 15, fg = lane >> 4;

    const int srow = wave * 8 + (lane >> 3);
    const int scol = 8 * ((lane & 7) ^ (lane >> 3));
    const f16* ga = A  + (long)(m0 + srow) * 4096 + scol;
    const f16* gb = Bt + (long)(n0 + srow) * 4096 + scol;
    const int dst0 = wave * 1024;

    auto STAGE = [&](int ktile, int c) {
        char* base = L + c * 65536;
        const f16* gat = ga + ktile * 64;
        const f16* gbt = gb + ktile * 64;
#pragma unroll
        for (int half = 0; half < 2; ++half)
#pragma unroll
            for (int inst = 0; inst < 2; ++inst) {
                async_ld16(gat + (long)(half * 128 + inst * 64) * 4096,
                           base + half * 16384 + inst * 8192 + dst0);
                async_ld16(gbt + (long)(half * 128 + inst * 64) * 4096,
                           base + 32768 + half * 16384 + inst * 8192 + dst0);
            }
    };

    // prologue: tiles 0 and 1 in flight; wait for tile 0 only
    STAGE(0, 0);
    STAGE(1, 1);
    asm volatile("s_waitcnt vmcnt(8)" ::: "memory");
    __builtin_amdgcn_s_barrier();
    __builtin_amdgcn_sched_barrier(0);

    const int aoff = wm * 16384;
    const int boff = 32768 + (wn >> 1) * 16384;
    const int brow = (wn & 1) * 64;
    const int swz = (fr & 7) << 4;
    const int cb0 = (16 * fg) ^ swz;
    const int cb1 = (64 + 16 * fg) ^ swz;

    f16x8 bfA[4], bfB[4], afX[4], afY[4];

    { // preload tile 0, phase 0 fragments (ks0; A mq0)
        const char* bufA = L + aoff;
        const char* bufB = L + boff;
#pragma unroll
        for (int nf = 0; nf < 4; ++nf)
            bfA[nf] = *(const f16x8*)(bufB + (brow + nf * 16 + fr) * 128 + cb0);
#pragma unroll
        for (int i = 0; i < 4; ++i)
            afX[i] = *(const f16x8*)(bufA + (i * 16 + fr) * 128 + cb0);
    }

    for (int kt = 0; kt < 64; ++kt) {
        const int c = kt & 1;
        const char* bufA = L + c * 65536 + aoff;
        const char* bufB = L + c * 65536 + boff;

        // ph0: prefetch (ks0,mq1)A + (ks1)B; MFMA afX*bfA -> acc[0..3]
#pragma unroll
        for (int i = 0; i < 4; ++i)
            afY[i] = *(const f16x8*)(bufA + ((64 + i * 16 + fr) * 128) + cb0);
#pragma unroll
        for (int nf = 0; nf < 4; ++nf)
            bfB[nf] = *(const f16x8*)(bufB + (brow + nf * 16 + fr) * 128 + cb1);
        __builtin_amdgcn_s_setprio(1);
#pragma unroll
        for (int i = 0; i < 4; ++i)
#pragma unroll
            for (int nf = 0; nf < 4; ++nf)
                acc[i][nf] = __builtin_amdgcn_mfma_f32_16x16x32_f16(
                    afX[i], bfA[nf], acc[i][nf], 0, 0, 0);
        __builtin_amdgcn_s_setprio(0);

        // ph1: prefetch (ks1,mq0)A; MFMA afY*bfA -> acc[4..7]
#pragma unroll
        for (int i = 0; i < 4; ++i)
            afX[i] = *(const f16x8*)(bufA + ((i * 16 + fr) * 128) + cb1);
        __builtin_amdgcn_s_setprio(1);
#pragma unroll
        for (int i = 0; i < 4; ++i)
#pragma unroll
            for (int nf = 0; nf < 4; ++nf)
                acc[4 + i][nf] = __builtin_amdgcn_mfma_f32_16x16x32_f16(
                    afY[i], bfA[nf], acc[4 + i][nf], 0, 0, 0);
        __builtin_amdgcn_s_setprio(0);

        // ph2: prefetch (ks1,mq1)A; MFMA afX*bfB -> acc[0..3]
#pragma unroll
        for (int i = 0; i < 4; ++i)
            afY[i] = *(const f16x8*)(bufA + ((64 + i * 16 + fr) * 128) + cb1);
        __builtin_amdgcn_s_setprio(1);
#pragma unroll
        for (int i = 0; i < 4; ++i)
#pragma unroll
            for (int nf = 0; nf < 4; ++nf)
                acc[i][nf] = __builtin_amdgcn_mfma_f32_16x16x32_f16(
                    afX[i], bfB[nf], acc[i][nf], 0, 0, 0);
        __builtin_amdgcn_s_setprio(0);

        // ph3: MFMA afY*bfB -> acc[4..7]
        __builtin_amdgcn_s_setprio(1);
#pragma unroll
        for (int i = 0; i < 4; ++i)
#pragma unroll
            for (int nf = 0; nf < 4; ++nf)
                acc[4 + i][nf] = __builtin_amdgcn_mfma_f32_16x16x32_f16(
                    afY[i], bfB[nf], acc[4 + i][nf], 0, 0, 0);
        __builtin_amdgcn_s_setprio(0);

        // ---- tile end: all waves done reading buf c -> stage t+2 into c
        __builtin_amdgcn_s_barrier();
        __builtin_amdgcn_sched_barrier(0);
        if (kt + 2 < 64) {
            STAGE(kt + 2, c);
            asm volatile("s_waitcnt vmcnt(8)" ::: "memory"); // t+1 landed, t+2 in flight
        } else if (kt + 1 < 64) {
            asm volatile("s_waitcnt vmcnt(0)" ::: "memory"); // drain last tile
        }
        __builtin_amdgcn_s_barrier();
        __builtin_amdgcn_sched_barrier(0);
        if (kt + 1 < 64) { // preload next tile's phase-0 fragments
            const char* nA = L + (c ^ 1) * 65536 + aoff;
            const char* nB = L + (c ^ 1) * 65536 + boff;
#pragma unroll
            for (int nf = 0; nf < 4; ++nf)
                bfA[nf] = *(const f16x8*)(nB + (brow + nf * 16 + fr) * 128 + cb0);
#pragma unroll
            for (int i = 0; i < 4; ++i)
                afX[i] = *(const f16x8*)(nA + (i * 16 + fr) * 128 + cb0);
        }
    }
}

// GEMM1: hidden[4096][4096] @ Wqkv^T[6144][4096] -> scatter q/k/v (Q pre-scaled)
__global__ __launch_bounds__(512) void k_gemm_qkv(
    const f16* __restrict__ A, const f16* __restrict__ Bt,
    f16* __restrict__ q, f16* __restrict__ kk_, f16* __restrict__ vv) {
    __shared__ __align__(16) char L[131072];
    const int bid = blockIdx.x;
    const int swzb = (bid & 7) * 48 + (bid >> 3);
    const int m0 = (swzb / 24) * 256, n0 = (swzb % 24) * 256;
    f32x4 acc[8][4] = {};
    gemm256_core(A, Bt, L, m0, n0, acc);

    const int lane = threadIdx.x & 63, wave = threadIdx.x >> 6;
    const int wm = wave >> 2, wn = wave & 3;
    const int fr = lane & 15, fg = lane >> 4;
#pragma unroll
    for (int mf = 0; mf < 8; ++mf) {
        int r0 = m0 + wm * 128 + mf * 16 + 4 * fg;
#pragma unroll
        for (int nf = 0; nf < 4; ++nf) {
            int cc = n0 + wn * 64 + nf * 16 + fr;
            int d = cc & 127;
#pragma unroll
            for (int e = 0; e < 4; ++e) {
                int r = r0 + e;
                int b = r >> 11, s = r & (Sn - 1);
                if (cc < 4096) {
                    int h = cc >> 7;
                    q[(((long)b * NH + h) * Sn + s) * HD + d] = (f16)(acc[mf][nf][e] * QSC);
                } else if (cc < 5120) {
                    int h = (cc - 4096) >> 7;
                    kk_[(((long)b * NKV + h) * Sn + s) * HD + d] = (f16)acc[mf][nf][e];
                } else {
                    int h = (cc - 5120) >> 7;
                    vv[(((long)b * NKV + h) * Sn + s) * HD + d] = (f16)acc[mf][nf][e];
                }
            }
        }
    }
}

// GEMM2: attn_out[4096][4096] @ wo^T[4096][4096] -> d_out f32
__global__ __launch_bounds__(512) void k_gemm_out(
    const f16* __restrict__ A, const f16* __restrict__ Bt,
    float* __restrict__ out) {
    __shared__ __align__(16) char L[131072];
    const int bid = blockIdx.x;
    const int swzb = (bid & 7) * 32 + (bid >> 3);
    const int m0 = (swzb >> 4) * 256, n0 = (swzb & 15) * 256;
    f32x4 acc[8][4] = {};
    gemm256_core(A, Bt, L, m0, n0, acc);

    const int lane = threadIdx.x & 63, wave = threadIdx.x >> 6;
    const int wm = wave >> 2, wn = wave & 3;
    const int fr = lane & 15, fg = lane >> 4;
#pragma unroll
    for (int mf = 0; mf < 8; ++mf) {
        int r0 = m0 + wm * 128 + mf * 16 + 4 * fg;
#pragma unroll
        for (int nf = 0; nf < 4; ++nf) {
            int cc = n0 + wn * 64 + nf * 16 + fr;
#pragma unroll
            for (int e = 0; e < 4; ++e)
                out[(long)(r0 + e) * 4096 + cc] = acc[mf][nf][e];
        }
    }
}

// ---------------------------------------------------------------------------
// Flash attention v4 (round-5 proven): swapped QK^T + in-lane softmax +
// defer-rescale, native v_exp, Psm[32][32] 2-phase PV, kvh-grouped grid,
// K/V dbuf + vmcnt(8) + XOR swizzle.

__device__ __forceinline__ f16x8 ld_sw256(const f16* base, int r, int c) {
    int byte = r * 256 + ((c * 2) ^ ((r & 7) << 4));
    return *(const f16x8*)((const char*)base + byte);
}
__device__ __forceinline__ f16x8 ld_sw128(const f16* base, int r, int c) {
    int byte = r * 128 + ((c * 2) ^ ((r & 7) << 4));
    return *(const f16x8*)((const char*)base + byte);
}

__device__ __forceinline__ void stage_k(const f16* __restrict__ Kb, f16* ksm,
                                        int k0, int wave, int lane) {
#pragma unroll
    for (int i = 0; i < 4; ++i) {
        int dbase = (i * 4 + wave) * 1024;
        int d = dbase + lane * 16;
        int row = d >> 8;
        int cb = (d & 255) ^ ((row & 7) << 4);
        async_ld16(Kb + (long)(k0 + row) * HD + (cb >> 1), (char*)ksm + dbase);
    }
}
__device__ __forceinline__ void stage_v(const f16* __restrict__ Vb, f16* vsm,
                                        int k0, int wave, int lane) {
#pragma unroll
    for (int i = 0; i < 4; ++i) {
        int dbase = (i * 4 + wave) * 1024;
        int d = dbase + lane * 16;
        int row = d >> 7;
        int cb = (d & 127) ^ ((row & 7) << 4);
        async_ld16(Vb + (long)row * Sn + k0 + (cb >> 1), (char*)vsm + dbase);
    }
}

__global__ __launch_bounds__(256) void k_attn(
    const f16* __restrict__ Q, const f16* __restrict__ K,
    const f16* __restrict__ Vt, f16* __restrict__ O) {
    __shared__ __align__(16) f16 Ksm[2][64 * 128];
    __shared__ __align__(16) f16 Vsm[2][128 * 64];
    __shared__ __align__(16) f16 Psm[4][32 * 32];

    const int id = blockIdx.x;
    const int kvh = id & 7;
    const int r_ = id >> 3;
    const int qt = 15 - (r_ & 15);
    const int hg = (r_ >> 4) & 3;
    const int b  = r_ >> 6;
    const int h  = kvh * 4 + hg;
    const int q0 = qt * 128;
    const int t = threadIdx.x, lane = t & 63, wave = t >> 6;
    const int q0w = q0 + wave * 32;
    const int fr = lane & 15, fg = lane >> 4;

    const f16* Qb = Q + ((long)(b * NH + h) * Sn) * HD;
    const f16* Kb = K + ((long)(b * NKV + kvh) * Sn) * HD;
    const f16* Vb = Vt + ((long)(b * NKV + kvh) * HD) * Sn;

    f16x8 qf[2][4];
#pragma unroll
    for (int mq = 0; mq < 2; ++mq)
#pragma unroll
        for (int kk = 0; kk < 4; ++kk)
            qf[mq][kk] = *(const f16x8*)&Qb[(long)(q0w + mq * 16 + fr) * HD + kk * 32 + 8 * fg];

    f32x4 oacc[2][8] = {};
    float mrun[2] = {-1e30f, -1e30f};
    float lrun[2] = {0.f, 0.f};

    const int nt = q0 / 64 + 2;
    stage_k(Kb, Ksm[0], 0, wave, lane);
    stage_v(Vb, Vsm[0], 0, wave, lane);

    for (int kt = 0; kt < nt; ++kt) {
        const int k0 = kt * 64;
        const int cur = kt & 1;
        if (kt + 1 < nt) {
            stage_k(Kb, Ksm[cur ^ 1], (kt + 1) * 64, wave, lane);
            stage_v(Vb, Vsm[cur ^ 1], (kt + 1) * 64, wave, lane);
            asm volatile("s_waitcnt vmcnt(8)" ::: "memory");
        } else {
            asm volatile("s_waitcnt vmcnt(0)" ::: "memory");
        }
        __builtin_amdgcn_s_barrier();

        if (k0 <= q0w + 31) {
            f32x4 st[4][2] = {};
#pragma unroll
            for (int kk = 0; kk < 4; ++kk)
#pragma unroll
                for (int nn = 0; nn < 4; ++nn) {
                    f16x8 kf = ld_sw256(Ksm[cur], nn * 16 + fr, kk * 32 + 8 * fg);
#pragma unroll
                    for (int mq = 0; mq < 2; ++mq)
                        st[nn][mq] = __builtin_amdgcn_mfma_f32_16x16x32_f16(
                            kf, qf[mq][kk], st[nn][mq], 0, 0, 0);
                }
            const bool full = (k0 + 63 <= q0w);
            if (!full) {
#pragma unroll
                for (int nn = 0; nn < 4; ++nn)
#pragma unroll
                    for (int mq = 0; mq < 2; ++mq)
#pragma unroll
                        for (int e = 0; e < 4; ++e) {
                            int kv = k0 + 16 * nn + 4 * fg + e;
                            int qq = q0w + 16 * mq + fr;
                            if (kv > qq) st[nn][mq][e] = -1e30f;
                        }
            }
            float pmax[2];
#pragma unroll
            for (int mq = 0; mq < 2; ++mq) {
                float m0v = fmaxf(fmaxf(st[0][mq][0], st[0][mq][1]),
                                  fmaxf(st[0][mq][2], st[0][mq][3]));
#pragma unroll
                for (int nn = 1; nn < 4; ++nn) {
                    float mv = fmaxf(fmaxf(st[nn][mq][0], st[nn][mq][1]),
                                     fmaxf(st[nn][mq][2], st[nn][mq][3]));
                    m0v = fmaxf(m0v, mv);
                }
                m0v = fmaxf(m0v, __shfl_xor(m0v, 16, 64));
                m0v = fmaxf(m0v, __shfl_xor(m0v, 32, 64));
                pmax[mq] = m0v;
            }
            bool need = (pmax[0] > mrun[0] + 8.f) || (pmax[1] > mrun[1] + 8.f);
            if (__any(need)) {
#pragma unroll
                for (int mq = 0; mq < 2; ++mq) {
                    float mn = fmaxf(mrun[mq], pmax[mq]);
                    float sc = fexp2(mrun[mq] - mn);
                    mrun[mq] = mn;
                    lrun[mq] *= sc;
                    float scr[4];
#pragma unroll
                    for (int e = 0; e < 4; ++e)
                        scr[e] = __shfl(sc, (lane & 48) | (4 * fg + e), 64);
#pragma unroll
                    for (int nd = 0; nd < 8; ++nd)
#pragma unroll
                        for (int e = 0; e < 4; ++e)
                            oacc[mq][nd][e] *= scr[e];
                }
            }
#pragma unroll
            for (int ph = 0; ph < 2; ++ph) {
#pragma unroll
                for (int mq = 0; mq < 2; ++mq) {
                    int row = 16 * mq + fr;
                    int rot = ((row >> 1) & 3) << 4;
                    char* pbase = (char*)&Psm[wave][0] + row * 64;
#pragma unroll
                    for (int nh = 0; nh < 2; ++nh) {
                        int nn = 2 * ph + nh;
                        float p0 = fexp2(st[nn][mq][0] - mrun[mq]);
                        float p1 = fexp2(st[nn][mq][1] - mrun[mq]);
                        float p2 = fexp2(st[nn][mq][2] - mrun[mq]);
                        float p3 = fexp2(st[nn][mq][3] - mrun[mq]);
                        lrun[mq] += (p0 + p1) + (p2 + p3);
                        uint2 w = {pk2(p0, p1), pk2(p2, p3)};
                        *(uint2*)(pbase + ((32 * nh + 8 * fg + rot) & 63)) = w;
                    }
                }
                asm volatile("s_waitcnt lgkmcnt(0)" ::: "memory");
                f16x8 pf[2];
#pragma unroll
                for (int mq = 0; mq < 2; ++mq) {
                    int row = 16 * mq + fr;
                    int rot = ((row >> 1) & 3) << 4;
                    pf[mq] = *(const f16x8*)((char*)&Psm[wave][0] + row * 64 +
                                             ((16 * fg + rot) & 63));
                }
#pragma unroll
                for (int nd = 0; nd < 8; ++nd) {
                    f16x8 vf = ld_sw128(Vsm[cur], nd * 16 + fr, ph * 32 + 8 * fg);
#pragma unroll
                    for (int mq = 0; mq < 2; ++mq)
                        oacc[mq][nd] = __builtin_amdgcn_mfma_f32_16x16x32_f16(
                            pf[mq], vf, oacc[mq][nd], 0, 0, 0);
                }
            }
        }
        __builtin_amdgcn_s_barrier();
    }

#pragma unroll
    for (int mq = 0; mq < 2; ++mq) {
        lrun[mq] += __shfl_xor(lrun[mq], 16, 64);
        lrun[mq] += __shfl_xor(lrun[mq], 32, 64);
    }
#pragma unroll
    for (int mq = 0; mq < 2; ++mq) {
        float li = 1.f / lrun[mq];
        float ir[4];
#pragma unroll
        for (int e = 0; e < 4; ++e)
            ir[e] = __shfl(li, (lane & 48) | (4 * fg + e), 64);
#pragma unroll
        for (int nd = 0; nd < 8; ++nd)
#pragma unroll
            for (int e = 0; e < 4; ++e) {
                int srow = q0w + mq * 16 + 4 * fg + e;
                long tok = (long)b * Sn + srow;
                O[tok * (NH * HD) + h * HD + nd * 16 + fr] = (f16)(oacc[mq][nd][e] * ir[e]);
            }
    }
}

// sentinel if workspace too small
__global__ void k_ws_fail(float* out) { out[0] = 1.0e9f; }

// ---------------------------------------------------------------------------
extern "C" void kernel_launch(void* const* d_in, const int* in_sizes, int n_in,
                              void* d_out, int out_size, void* d_ws, size_t ws_size,
                              hipStream_t stream) {
    const float* hs   = (const float*)d_in[0];
    const float* wq   = (const float*)d_in[1];
    const float* wk   = (const float*)d_in[2];
    const float* wv   = (const float*)d_in[3];
    const float* wo   = (const float*)d_in[4];
    const float* cosb = (const float*)d_in[5];
    const float* sinb = (const float*)d_in[6];
    float* out = (float*)d_out;

    const size_t OFF_WQKV = 0;
    const size_t OFF_WO   = 50331648;
    const size_t OFF_HID  = 83886080;
    const size_t OFF_Q    = 117440512;
    const size_t OFF_K    = 150994944;
    const size_t OFF_V    = 159383552;
    const size_t OFF_VT   = 167772160;
    const size_t WS_NEED  = 176160768;
    if (ws_size < WS_NEED) { k_ws_fail<<<1, 1, 0, stream>>>(out); return; }

    char* ws = (char*)d_ws;
    f16* wqkv_t = (f16*)(ws + OFF_WQKV);
    f16* wo_t   = (f16*)(ws + OFF_WO);
    f16* hid    = (f16*)(ws + OFF_HID);
    f16* qb     = (f16*)(ws + OFF_Q);
    f16* kb     = (f16*)(ws + OFF_K);
    f16* vb     = (f16*)(ws + OFF_V);
    f16* vtb    = (f16*)(ws + OFF_VT);

    dim3 tb(32, 8);
    k_cvt<<<dim3(16777216 / (256 * 8)), 256, 0, stream>>>(hs, hid, 16777216L);
    k_tcvt<<<dim3(128, 128), tb, 0, stream>>>(wq, wqkv_t, 4096, 4096, 4096);
    k_tcvt<<<dim3(32, 128),  tb, 0, stream>>>(wk, wqkv_t + (long)4096 * 4096, 4096, 1024, 4096);
    k_tcvt<<<dim3(32, 128),  tb, 0, stream>>>(wv, wqkv_t + (long)5120 * 4096, 4096, 1024, 4096);
    k_tcvt<<<dim3(128, 128), tb, 0, stream>>>(wo, wo_t, 4096, 4096, 4096);
    k_gemm_qkv<<<dim3(384), 512, 0, stream>>>(hid, wqkv_t, qb, kb, vb);
    k_rope<<<dim3(2 * 32 * 2048 * 32 / 256), 256, 0, stream>>>(qb, cosb, sinb, NH);
    k_rope<<<dim3(2 * 8 * 2048 * 32 / 256), 256, 0, stream>>>(kb, cosb, sinb, NKV);
    k_tv<<<dim3(64, 4, 16), tb, 0, stream>>>(vb, vtb);
    k_attn<<<dim3(1024), 256, 0, stream>>>(qb, kb, vtb, hid);
    k_gemm_out<<<dim3(256), 512, 0, stream>>>(hid, wo_t, out);
}

// Round 7
// 675.771 us; speedup vs baseline: 1.0076x; 1.0076x over previous
//
#include <hip/hip_runtime.h>

// ============================================================================
// GLM4-MoE attention layer on MI355X (gfx950), fp16 MFMA pipeline.
// Round 7: occupancy-first GEMM. r4-r6 all landed at 35% MfmaUtil because a
// single 128KB block per CU barrier-locksteps 2 waves/SIMD: LDS bursts and
// MFMA bursts serialize. Fix via TLP: tile 128x256, BK=64, single-buffer LDS
// 48KB, acc 64 VGPR, __launch_bounds__(512,4) -> 2 blocks/CU; per-tile
// schedule is just STAGE -> syncthreads -> MFMA -> syncthreads (the co-resident
// block covers the stalls, m114). Grids are integer blocks/CU: GEMM1 768=3/CU,
// GEMM2 512=2/CU (kills the 75% tail of 384/256). Attention/aux unchanged.
// ============================================================================

typedef _Float16 f16;
typedef _Float16 f16x8 __attribute__((ext_vector_type(8)));
typedef float f32x4 __attribute__((ext_vector_type(4)));

static constexpr int Bn = 2, Sn = 2048, Hn = 4096, NH = 32, NKV = 8, HD = 128;
static constexpr float QSC = 0.08838834764831845f * 1.44269504088896340736f; // 1/sqrt(128)*log2e

#define AS1 __attribute__((address_space(1)))
#define AS3 __attribute__((address_space(3)))

__device__ __forceinline__ void async_ld16(const void* g, void* l) {
    __builtin_amdgcn_global_load_lds((const AS1 void*)g, (AS3 void*)l, 16, 0, 0);
}

__device__ __forceinline__ unsigned pk2(float a, float b) {
    unsigned r;
    asm("v_cvt_pkrtz_f16_f32 %0, %1, %2" : "=v"(r) : "v"(a), "v"(b));
    return r;
}

// native exp2: v_exp_f32 computes 2^x
__device__ __forceinline__ float fexp2(float x) {
    float r;
    asm("v_exp_f32 %0, %1" : "=v"(r) : "v"(x));
    return r;
}

// ---------------------------------------------------------------------------
__global__ void k_cvt(const float* __restrict__ src, f16* __restrict__ dst, long n) {
    long i = ((long)blockIdx.x * blockDim.x + threadIdx.x) * 8;
    if (i >= n) return;
    float4 a = *(const float4*)(src + i);
    float4 b = *(const float4*)(src + i + 4);
    f16x8 o = {(f16)a.x, (f16)a.y, (f16)a.z, (f16)a.w,
               (f16)b.x, (f16)b.y, (f16)b.z, (f16)b.w};
    *(f16x8*)(dst + i) = o;
}

// ---------------------------------------------------------------------------
__global__ void k_tcvt(const float* __restrict__ src, f16* __restrict__ dst,
                       int K, int N, long rs) {
    __shared__ float tile[32][33];
    int k0 = blockIdx.y * 32, n0 = blockIdx.x * 32;
    int tx = threadIdx.x, ty = threadIdx.y;
#pragma unroll
    for (int r = ty; r < 32; r += 8)
        tile[r][tx] = src[(long)(k0 + r) * N + (n0 + tx)];
    __syncthreads();
#pragma unroll
    for (int r = ty; r < 32; r += 8)
        dst[(long)(n0 + r) * rs + (k0 + tx)] = (f16)tile[tx][r];
}

// ---------------------------------------------------------------------------
__global__ void k_rope(f16* __restrict__ x, const float* __restrict__ cosb,
                       const float* __restrict__ sinb, int nheads) {
    long idx = (long)blockIdx.x * blockDim.x + threadIdx.x;
    int i = (int)(idx & 31);
    long t = idx >> 5;
    int s = (int)(t & (Sn - 1));
    int bh = (int)(t >> 11);
    int b = bh / nheads;
    long base = t * HD + 2 * i;
    float c = cosb[((long)b * Sn + s) * 64 + i];
    float sv = sinb[((long)b * Sn + s) * 64 + i];
    float x0 = (float)x[base], x1 = (float)x[base + 1];
    x[base]     = (f16)(x0 * c - x1 * sv);
    x[base + 1] = (f16)(x1 * c + x0 * sv);
}

// ---------------------------------------------------------------------------
__global__ void k_tv(const f16* __restrict__ v, f16* __restrict__ vt) {
    __shared__ f16 tile[32][33];
    int bk = blockIdx.z;
    int s0 = blockIdx.x * 32, d0 = blockIdx.y * 32;
    const f16* src = v + (long)bk * Sn * HD;
    f16* dst = vt + (long)bk * Sn * HD;
    int tx = threadIdx.x, ty = threadIdx.y;
#pragma unroll
    for (int r = ty; r < 32; r += 8)
        tile[r][tx] = src[(long)(s0 + r) * HD + (d0 + tx)];
    __syncthreads();
#pragma unroll
    for (int r = ty; r < 32; r += 8)
        dst[(long)(d0 + r) * Sn + (s0 + tx)] = tile[tx][r];
}

// ---------------------------------------------------------------------------
// 128x256 GEMM core, BK=64, 8 waves (2M x 4N, each 64x64), K=4096 fixed.
// Single-buffer LDS 48KB: A [128][64] at 0 (128B rows), B [256][64] at 16384.
// Rows swizzled: logical (r, colbyte cb) at byte r*128 + (cb ^ ((r&7)<<4));
// staging keeps LDS dest linear and inverse-swizzles the global source.
// Per K-tile: STAGE(6 gload_lds) -> syncthreads (drains vm) -> 32 MFMA
// -> syncthreads. Cross-block TLP (2 blocks/CU) hides the stage drain.
__device__ __forceinline__ void gemm_core(
    const f16* __restrict__ A, const f16* __restrict__ Bt,
    char* L, int m0, int n0, f32x4 acc[4][4]) {
    const int t = threadIdx.x, lane = t & 63, wave = t >> 6;
    const int wm = wave >> 2, wn = wave & 3;
    const int fr = lane & 15, fg = lane >> 4;

    // staging sources (linear LDS dest; source col pre-swizzled)
    const f16* gsa[2];
    const f16* gsb[4];
#pragma unroll
    for (int i = 0; i < 2; ++i) {
        int d = i * 8192 + t * 16;
        int row = d >> 7, cb = (d & 127) ^ ((row & 7) << 4);
        gsa[i] = A + (long)(m0 + row) * 4096 + (cb >> 1);
    }
#pragma unroll
    for (int i = 0; i < 4; ++i) {
        int d = i * 8192 + t * 16;
        int row = d >> 7, cb = (d & 127) ^ ((row & 7) << 4);
        gsb[i] = Bt + (long)(n0 + row) * 4096 + (cb >> 1);
    }
    const int dst0 = wave * 1024;   // wave-uniform; HW adds lane*16

    for (int kt = 0; kt < 64; ++kt) {
        const int ko = kt * 64;
#pragma unroll
        for (int i = 0; i < 2; ++i)
            async_ld16(gsa[i] + ko, L + i * 8192 + dst0);
#pragma unroll
        for (int i = 0; i < 4; ++i)
            async_ld16(gsb[i] + ko, L + 16384 + i * 8192 + dst0);
        __syncthreads();   // waits vmcnt(0): tile staged; barrier

#pragma unroll
        for (int ks = 0; ks < 2; ++ks) {
            const int cb = ks * 64 + 16 * fg;
            f16x8 bf[4], af[4];
#pragma unroll
            for (int nf = 0; nf < 4; ++nf) {
                int r = wn * 64 + nf * 16 + fr;
                bf[nf] = *(const f16x8*)(L + 16384 + r * 128 + (cb ^ ((r & 7) << 4)));
            }
#pragma unroll
            for (int mf = 0; mf < 4; ++mf) {
                int r = wm * 64 + mf * 16 + fr;
                af[mf] = *(const f16x8*)(L + r * 128 + (cb ^ ((r & 7) << 4)));
            }
            __builtin_amdgcn_s_setprio(1);
#pragma unroll
            for (int mf = 0; mf < 4; ++mf)
#pragma unroll
                for (int nf = 0; nf < 4; ++nf)
                    acc[mf][nf] = __builtin_amdgcn_mfma_f32_16x16x32_f16(
                        af[mf], bf[nf], acc[mf][nf], 0, 0, 0);
            __builtin_amdgcn_s_setprio(0);
        }
        __syncthreads();   // frag reads done before next tile's stage
    }
}

// GEMM1: hidden[4096][4096] @ Wqkv^T[6144][4096] -> scatter q/k/v (Q pre-scaled)
// grid 768 = 3 blocks/CU exactly; n-major per-XCD chunks (B panel ~6MB/XCD).
__global__ __launch_bounds__(512, 4) void k_gemm_qkv(
    const f16* __restrict__ A, const f16* __restrict__ Bt,
    f16* __restrict__ q, f16* __restrict__ kk_, f16* __restrict__ vv) {
    __shared__ __align__(16) char L[49152];
    const int xcd = blockIdx.x & 7, i = blockIdx.x >> 3;   // i in [0,96)
    const int n0 = (xcd * 3 + (i >> 5)) * 256;
    const int m0 = (i & 31) * 128;
    f32x4 acc[4][4] = {};
    gemm_core(A, Bt, L, m0, n0, acc);

    const int lane = threadIdx.x & 63, wave = threadIdx.x >> 6;
    const int wm = wave >> 2, wn = wave & 3;
    const int fr = lane & 15, fg = lane >> 4;
#pragma unroll
    for (int mf = 0; mf < 4; ++mf) {
        int r0 = m0 + wm * 64 + mf * 16 + 4 * fg;
#pragma unroll
        for (int nf = 0; nf < 4; ++nf) {
            int cc = n0 + wn * 64 + nf * 16 + fr;
            int d = cc & 127;
#pragma unroll
            for (int e = 0; e < 4; ++e) {
                int r = r0 + e;
                int b = r >> 11, s = r & (Sn - 1);
                if (cc < 4096) {
                    int h = cc >> 7;
                    q[(((long)b * NH + h) * Sn + s) * HD + d] = (f16)(acc[mf][nf][e] * QSC);
                } else if (cc < 5120) {
                    int h = (cc - 4096) >> 7;
                    kk_[(((long)b * NKV + h) * Sn + s) * HD + d] = (f16)acc[mf][nf][e];
                } else {
                    int h = (cc - 5120) >> 7;
                    vv[(((long)b * NKV + h) * Sn + s) * HD + d] = (f16)acc[mf][nf][e];
                }
            }
        }
    }
}

// GEMM2: attn_out[4096][4096] @ wo^T[4096][4096] -> d_out f32
// grid 512 = 2 blocks/CU exactly.
__global__ __launch_bounds__(512, 4) void k_gemm_out(
    const f16* __restrict__ A, const f16* __restrict__ Bt,
    float* __restrict__ out) {
    __shared__ __align__(16) char L[49152];
    const int xcd = blockIdx.x & 7, i = blockIdx.x >> 3;   // i in [0,64)
    const int n0 = (xcd * 2 + (i >> 5)) * 256;
    const int m0 = (i & 31) * 128;
    f32x4 acc[4][4] = {};
    gemm_core(A, Bt, L, m0, n0, acc);

    const int lane = threadIdx.x & 63, wave = threadIdx.x >> 6;
    const int wm = wave >> 2, wn = wave & 3;
    const int fr = lane & 15, fg = lane >> 4;
#pragma unroll
    for (int mf = 0; mf < 4; ++mf) {
        int r0 = m0 + wm * 64 + mf * 16 + 4 * fg;
#pragma unroll
        for (int nf = 0; nf < 4; ++nf) {
            int cc = n0 + wn * 64 + nf * 16 + fr;
#pragma unroll
            for (int e = 0; e < 4; ++e)
                out[(long)(r0 + e) * 4096 + cc] = acc[mf][nf][e];
        }
    }
}

// ---------------------------------------------------------------------------
// Flash attention v4 (round-5 proven): swapped QK^T + in-lane softmax +
// defer-rescale, native v_exp, Psm[32][32] 2-phase PV, kvh-grouped grid,
// K/V dbuf + vmcnt(8) + XOR swizzle.

__device__ __forceinline__ f16x8 ld_sw256(const f16* base, int r, int c) {
    int byte = r * 256 + ((c * 2) ^ ((r & 7) << 4));
    return *(const f16x8*)((const char*)base + byte);
}
__device__ __forceinline__ f16x8 ld_sw128(const f16* base, int r, int c) {
    int byte = r * 128 + ((c * 2) ^ ((r & 7) << 4));
    return *(const f16x8*)((const char*)base + byte);
}

__device__ __forceinline__ void stage_k(const f16* __restrict__ Kb, f16* ksm,
                                        int k0, int wave, int lane) {
#pragma unroll
    for (int i = 0; i < 4; ++i) {
        int dbase = (i * 4 + wave) * 1024;
        int d = dbase + lane * 16;
        int row = d >> 8;
        int cb = (d & 255) ^ ((row & 7) << 4);
        async_ld16(Kb + (long)(k0 + row) * HD + (cb >> 1), (char*)ksm + dbase);
    }
}
__device__ __forceinline__ void stage_v(const f16* __restrict__ Vb, f16* vsm,
                                        int k0, int wave, int lane) {
#pragma unroll
    for (int i = 0; i < 4; ++i) {
        int dbase = (i * 4 + wave) * 1024;
        int d = dbase + lane * 16;
        int row = d >> 7;
        int cb = (d & 127) ^ ((row & 7) << 4);
        async_ld16(Vb + (long)row * Sn + k0 + (cb >> 1), (char*)vsm + dbase);
    }
}

__global__ __launch_bounds__(256) void k_attn(
    const f16* __restrict__ Q, const f16* __restrict__ K,
    const f16* __restrict__ Vt, f16* __restrict__ O) {
    __shared__ __align__(16) f16 Ksm[2][64 * 128];
    __shared__ __align__(16) f16 Vsm[2][128 * 64];
    __shared__ __align__(16) f16 Psm[4][32 * 32];

    const int id = blockIdx.x;
    const int kvh = id & 7;
    const int r_ = id >> 3;
    const int qt = 15 - (r_ & 15);
    const int hg = (r_ >> 4) & 3;
    const int b  = r_ >> 6;
    const int h  = kvh * 4 + hg;
    const int q0 = qt * 128;
    const int t = threadIdx.x, lane = t & 63, wave = t >> 6;
    const int q0w = q0 + wave * 32;
    const int fr = lane & 15, fg = lane >> 4;

    const f16* Qb = Q + ((long)(b * NH + h) * Sn) * HD;
    const f16* Kb = K + ((long)(b * NKV + kvh) * Sn) * HD;
    const f16* Vb = Vt + ((long)(b * NKV + kvh) * HD) * Sn;

    f16x8 qf[2][4];
#pragma unroll
    for (int mq = 0; mq < 2; ++mq)
#pragma unroll
        for (int kk = 0; kk < 4; ++kk)
            qf[mq][kk] = *(const f16x8*)&Qb[(long)(q0w + mq * 16 + fr) * HD + kk * 32 + 8 * fg];

    f32x4 oacc[2][8] = {};
    float mrun[2] = {-1e30f, -1e30f};
    float lrun[2] = {0.f, 0.f};

    const int nt = q0 / 64 + 2;
    stage_k(Kb, Ksm[0], 0, wave, lane);
    stage_v(Vb, Vsm[0], 0, wave, lane);

    for (int kt = 0; kt < nt; ++kt) {
        const int k0 = kt * 64;
        const int cur = kt & 1;
        if (kt + 1 < nt) {
            stage_k(Kb, Ksm[cur ^ 1], (kt + 1) * 64, wave, lane);
            stage_v(Vb, Vsm[cur ^ 1], (kt + 1) * 64, wave, lane);
            asm volatile("s_waitcnt vmcnt(8)" ::: "memory");
        } else {
            asm volatile("s_waitcnt vmcnt(0)" ::: "memory");
        }
        __builtin_amdgcn_s_barrier();

        if (k0 <= q0w + 31) {
            f32x4 st[4][2] = {};
#pragma unroll
            for (int kk = 0; kk < 4; ++kk)
#pragma unroll
                for (int nn = 0; nn < 4; ++nn) {
                    f16x8 kf = ld_sw256(Ksm[cur], nn * 16 + fr, kk * 32 + 8 * fg);
#pragma unroll
                    for (int mq = 0; mq < 2; ++mq)
                        st[nn][mq] = __builtin_amdgcn_mfma_f32_16x16x32_f16(
                            kf, qf[mq][kk], st[nn][mq], 0, 0, 0);
                }
            const bool full = (k0 + 63 <= q0w);
            if (!full) {
#pragma unroll
                for (int nn = 0; nn < 4; ++nn)
#pragma unroll
                    for (int mq = 0; mq < 2; ++mq)
#pragma unroll
                        for (int e = 0; e < 4; ++e) {
                            int kv = k0 + 16 * nn + 4 * fg + e;
                            int qq = q0w + 16 * mq + fr;
                            if (kv > qq) st[nn][mq][e] = -1e30f;
                        }
            }
            float pmax[2];
#pragma unroll
            for (int mq = 0; mq < 2; ++mq) {
                float m0v = fmaxf(fmaxf(st[0][mq][0], st[0][mq][1]),
                                  fmaxf(st[0][mq][2], st[0][mq][3]));
#pragma unroll
                for (int nn = 1; nn < 4; ++nn) {
                    float mv = fmaxf(fmaxf(st[nn][mq][0], st[nn][mq][1]),
                                     fmaxf(st[nn][mq][2], st[nn][mq][3]));
                    m0v = fmaxf(m0v, mv);
                }
                m0v = fmaxf(m0v, __shfl_xor(m0v, 16, 64));
                m0v = fmaxf(m0v, __shfl_xor(m0v, 32, 64));
                pmax[mq] = m0v;
            }
            bool need = (pmax[0] > mrun[0] + 8.f) || (pmax[1] > mrun[1] + 8.f);
            if (__any(need)) {
#pragma unroll
                for (int mq = 0; mq < 2; ++mq) {
                    float mn = fmaxf(mrun[mq], pmax[mq]);
                    float sc = fexp2(mrun[mq] - mn);
                    mrun[mq] = mn;
                    lrun[mq] *= sc;
                    float scr[4];
#pragma unroll
                    for (int e = 0; e < 4; ++e)
                        scr[e] = __shfl(sc, (lane & 48) | (4 * fg + e), 64);
#pragma unroll
                    for (int nd = 0; nd < 8; ++nd)
#pragma unroll
                        for (int e = 0; e < 4; ++e)
                            oacc[mq][nd][e] *= scr[e];
                }
            }
#pragma unroll
            for (int ph = 0; ph < 2; ++ph) {
#pragma unroll
                for (int mq = 0; mq < 2; ++mq) {
                    int row = 16 * mq + fr;
                    int rot = ((row >> 1) & 3) << 4;
                    char* pbase = (char*)&Psm[wave][0] + row * 64;
#pragma unroll
                    for (int nh = 0; nh < 2; ++nh) {
                        int nn = 2 * ph + nh;
                        float p0 = fexp2(st[nn][mq][0] - mrun[mq]);
                        float p1 = fexp2(st[nn][mq][1] - mrun[mq]);
                        float p2 = fexp2(st[nn][mq][2] - mrun[mq]);
                        float p3 = fexp2(st[nn][mq][3] - mrun[mq]);
                        lrun[mq] += (p0 + p1) + (p2 + p3);
                        uint2 w = {pk2(p0, p1), pk2(p2, p3)};
                        *(uint2*)(pbase + ((32 * nh + 8 * fg + rot) & 63)) = w;
                    }
                }
                asm volatile("s_waitcnt lgkmcnt(0)" ::: "memory");
                f16x8 pf[2];
#pragma unroll
                for (int mq = 0; mq < 2; ++mq) {
                    int row = 16 * mq + fr;
                    int rot = ((row >> 1) & 3) << 4;
                    pf[mq] = *(const f16x8*)((char*)&Psm[wave][0] + row * 64 +
                                             ((16 * fg + rot) & 63));
                }
#pragma unroll
                for (int nd = 0; nd < 8; ++nd) {
                    f16x8 vf = ld_sw128(Vsm[cur], nd * 16 + fr, ph * 32 + 8 * fg);
#pragma unroll
                    for (int mq = 0; mq < 2; ++mq)
                        oacc[mq][nd] = __builtin_amdgcn_mfma_f32_16x16x32_f16(
                            pf[mq], vf, oacc[mq][nd], 0, 0, 0);
                }
            }
        }
        __builtin_amdgcn_s_barrier();
    }

#pragma unroll
    for (int mq = 0; mq < 2; ++mq) {
        lrun[mq] += __shfl_xor(lrun[mq], 16, 64);
        lrun[mq] += __shfl_xor(lrun[mq], 32, 64);
    }
#pragma unroll
    for (int mq = 0; mq < 2; ++mq) {
        float li = 1.f / lrun[mq];
        float ir[4];
#pragma unroll
        for (int e = 0; e < 4; ++e)
            ir[e] = __shfl(li, (lane & 48) | (4 * fg + e), 64);
#pragma unroll
        for (int nd = 0; nd < 8; ++nd)
#pragma unroll
            for (int e = 0; e < 4; ++e) {
                int srow = q0w + mq * 16 + 4 * fg + e;
                long tok = (long)b * Sn + srow;
                O[tok * (NH * HD) + h * HD + nd * 16 + fr] = (f16)(oacc[mq][nd][e] * ir[e]);
            }
    }
}

// sentinel if workspace too small
__global__ void k_ws_fail(float* out) { out[0] = 1.0e9f; }

// ---------------------------------------------------------------------------
extern "C" void kernel_launch(void* const* d_in, const int* in_sizes, int n_in,
                              void* d_out, int out_size, void* d_ws, size_t ws_size,
                              hipStream_t stream) {
    const float* hs   = (const float*)d_in[0];
    const float* wq   = (const float*)d_in[1];
    const float* wk   = (const float*)d_in[2];
    const float* wv   = (const float*)d_in[3];
    const float* wo   = (const float*)d_in[4];
    const float* cosb = (const float*)d_in[5];
    const float* sinb = (const float*)d_in[6];
    float* out = (float*)d_out;

    const size_t OFF_WQKV = 0;
    const size_t OFF_WO   = 50331648;
    const size_t OFF_HID  = 83886080;
    const size_t OFF_Q    = 117440512;
    const size_t OFF_K    = 150994944;
    const size_t OFF_V    = 159383552;
    const size_t OFF_VT   = 167772160;
    const size_t WS_NEED  = 176160768;
    if (ws_size < WS_NEED) { k_ws_fail<<<1, 1, 0, stream>>>(out); return; }

    char* ws = (char*)d_ws;
    f16* wqkv_t = (f16*)(ws + OFF_WQKV);
    f16* wo_t   = (f16*)(ws + OFF_WO);
    f16* hid    = (f16*)(ws + OFF_HID);
    f16* qb     = (f16*)(ws + OFF_Q);
    f16* kb     = (f16*)(ws + OFF_K);
    f16* vb     = (f16*)(ws + OFF_V);
    f16* vtb    = (f16*)(ws + OFF_VT);

    dim3 tb(32, 8);
    k_cvt<<<dim3(16777216 / (256 * 8)), 256, 0, stream>>>(hs, hid, 16777216L);
    k_tcvt<<<dim3(128, 128), tb, 0, stream>>>(wq, wqkv_t, 4096, 4096, 4096);
    k_tcvt<<<dim3(32, 128),  tb, 0, stream>>>(wk, wqkv_t + (long)4096 * 4096, 4096, 1024, 4096);
    k_tcvt<<<dim3(32, 128),  tb, 0, stream>>>(wv, wqkv_t + (long)5120 * 4096, 4096, 1024, 4096);
    k_tcvt<<<dim3(128, 128), tb, 0, stream>>>(wo, wo_t, 4096, 4096, 4096);
    k_gemm_qkv<<<dim3(768), 512, 0, stream>>>(hid, wqkv_t, qb, kb, vb);
    k_rope<<<dim3(2 * 32 * 2048 * 32 / 256), 256, 0, stream>>>(qb, cosb, sinb, NH);
    k_rope<<<dim3(2 * 8 * 2048 * 32 / 256), 256, 0, stream>>>(kb, cosb, sinb, NKV);
    k_tv<<<dim3(64, 4, 16), tb, 0, stream>>>(vb, vtb);
    k_attn<<<dim3(1024), 256, 0, stream>>>(qb, kb, vtb, hid);
    k_gemm_out<<<dim3(512), 512, 0, stream>>>(hid, wo_t, out);
}